// Round 11
// baseline (828.299 us; speedup 1.0000x reference)
//
#include <hip/hip_runtime.h>

// ---------------------------------------------------------------------------
// FCGRU (fp32 globals; bf16 in MFMA frags):
//   input(1024,128,32) -> FC(32->256) -> FC(256->512) -> GRU(512) over T=128
//   -> relu -> FC(512->256)+relu -> per-cultivar head (256->16)
// Input-side linears collapse: gx = input @ (W_ih@W2@W1).T + b_eff  (K=32 MFMA).
// Persistent GRU: 32 groups x 8 col-blocks (32 batches/group, 64 cols/block).
// Exchange medium per group, chosen by a runtime handshake that tests the
// EXACT mechanism used in the loop (remote plain store -> global_load_lds
// aux=sc0 freshness, incl. deliberate L1-population attempt):
//   FAST: h through the XCD's shared L2: plain write-through stores,
//         global_load_lds(aux=1) DMA staging (L1-bypass), workgroup-scope
//         atomic flags (RMW executes at L2). Zero MALL crossings per step.
//   SLOW: sc1 relaxed-agent atomics via MALL (r7 path, always correct).
// No inline asm anywhere. W_hh B-frags register-resident (48 short8/wave).
// Slab pitch 520 u16: 16B-aligned rows (DMA) + conflict-free ds_read_b128.
// ---------------------------------------------------------------------------

#define T_STEPS 128
#define PITCH   520
#define SLAB_ROWS 32

typedef __attribute__((ext_vector_type(8))) short short8;
typedef __attribute__((ext_vector_type(4))) float f32x4;
typedef __attribute__((ext_vector_type(4))) float float4v;
typedef unsigned short u16;
typedef unsigned long long u64;

// DMA global->LDS with aux=1 (sc0: L1-bypass, coherent at the XCD L2)
#define DMA16(g, l) __builtin_amdgcn_global_load_lds( \
    (const __attribute__((address_space(1))) void*)(g), \
    (__attribute__((address_space(3))) void*)(l), 16, 0, 1)
#define DMA4(g, l) __builtin_amdgcn_global_load_lds( \
    (const __attribute__((address_space(1))) void*)(g), \
    (__attribute__((address_space(3))) void*)(l), 4, 0, 1)

static __device__ __forceinline__ u16 f2bf(float f) {
    unsigned int u = __builtin_bit_cast(unsigned int, f);
    u += 0x7FFFu + ((u >> 16) & 1u);          // round-to-nearest-even
    return (u16)(u >> 16);
}
static __device__ __forceinline__ f32x4 mfma16(short8 a, short8 b, f32x4 c) {
    return __builtin_amdgcn_mfma_f32_16x16x32_bf16(a, b, c, 0, 0, 0);
}
// MALL (agent) path: relaxed agent atomics -> sc1 ld/st
static __device__ __forceinline__ void st_h16(u16* p, short8 v) {
    struct W { u64 a, b; } w = __builtin_bit_cast(W, v);
    u64* q = (u64*)p;
    __hip_atomic_store(q + 0, w.a, __ATOMIC_RELAXED, __HIP_MEMORY_SCOPE_AGENT);
    __hip_atomic_store(q + 1, w.b, __ATOMIC_RELAXED, __HIP_MEMORY_SCOPE_AGENT);
}
static __device__ __forceinline__ u64 ld_sc1_u64(const u16* p) {
    return __hip_atomic_load((const u64*)p, __ATOMIC_RELAXED, __HIP_MEMORY_SCOPE_AGENT);
}

// ---------------- workspace layout (bytes) ----------------
#define WS_HBUF0 0           // 1024*512*2 bf16 h buffer 0
#define WS_HBUF1 1048576     // 1024*512*2 bf16 h buffer 1
#define WS_W21   2097152     // 512*32*4 fp32 W2@W1
#define WS_B21   2162688     // 512*4
#define WS_WEFF  2164736     // 1536*32*2 bf16 W_ih@W2@W1
#define WS_BEFF  2263040     // 1536*4
#define WS_SFLAG 2269184     // slow flags: 32 groups x 8 x 4B
#define WS_FFLAG 2270208     // fast flags: 32 groups x 128B (32 u32 stride)
#define WS_TEST  2274304     // handshake rows: 32 groups x 256B
#define WS_OK    2282496     // ok bits: 32 groups x 8 x 4B
#define WS_TOKS  2283520     // tokens: 32 x 4B

// ---------------- prologue 0: W21 = W2@W1; b21; zero sync state (sc1/MALL)
__global__ void k_prep0(const float* __restrict__ W1, const float* __restrict__ b1,
                        const float* __restrict__ W2, const float* __restrict__ b2,
                        float* __restrict__ W21, float* __restrict__ b21,
                        unsigned* __restrict__ sflags, unsigned* __restrict__ fflags) {
    if (blockIdx.x == 0) {
        int t = threadIdx.x;
        __hip_atomic_store(&sflags[t], 0u, __ATOMIC_RELAXED, __HIP_MEMORY_SCOPE_AGENT);
        __hip_atomic_store(&fflags[(t >> 3) * 32 + (t & 7)], 0u, __ATOMIC_RELAXED, __HIP_MEMORY_SCOPE_AGENT);
    }
    int gid = blockIdx.x * 256 + threadIdx.x;   // 64 blocks: 512*32 outputs
    int k = gid >> 5, d = gid & 31;
    float acc = 0.f;
    for (int j = 0; j < 256; ++j)
        acc += W2[k * 256 + j] * W1[j * 32 + d];
    W21[k * 32 + d] = acc;
    if (d == 0) {
        float bb = b2[k];
        for (int j = 0; j < 256; ++j) bb += W2[k * 256 + j] * b1[j];
        b21[k] = bb;
    }
}

// ---------------- prologue 1: Weff = bf16(W_ih@W21); beff = W_ih@b21 + b_ih
__global__ void k_prep1(const float* __restrict__ W_ih, const float* __restrict__ b_ih,
                        const float* __restrict__ W21, const float* __restrict__ b21,
                        u16* __restrict__ Weff, float* __restrict__ beff) {
    int gid = blockIdx.x * 256 + threadIdx.x;   // 192 blocks: 1536*32 outputs
    int g = gid >> 5, d = gid & 31;
    float acc = 0.f;
    for (int k = 0; k < 512; ++k)
        acc += W_ih[g * 512 + k] * W21[k * 32 + d];
    Weff[g * 32 + d] = f2bf(acc);
    if (d == 0) {
        float bb = b_ih[g];
        for (int k = 0; k < 512; ++k) bb += W_ih[g * 512 + k] * b21[k];
        beff[g] = bb;
    }
}

// ---------------- slow (MALL) flag barrier — r7-proven mechanism ----------
static __device__ __forceinline__ void bar_arrive_slow(unsigned* gflags, int slot, unsigned v) {
    __syncthreads();      // drains vmcnt(0): all waves' stores committed
    if (threadIdx.x == 0)
        __hip_atomic_store(&gflags[slot], v, __ATOMIC_RELAXED, __HIP_MEMORY_SCOPE_AGENT);
}
static __device__ __forceinline__ void bar_wait_slow(const unsigned* gflags, unsigned v) {
    if (threadIdx.x < 64) {
        int idx = threadIdx.x & 7;
        for (;;) {
            unsigned f = __hip_atomic_load(&gflags[idx], __ATOMIC_RELAXED, __HIP_MEMORY_SCOPE_AGENT);
            if (__ballot(f >= v) == ~0ull) break;
            __builtin_amdgcn_s_sleep(1);
        }
    }
    __syncthreads();
}
// ---------------- fast (XCD-L2) flag wait: wg-scope RMWs execute at L2 ------
static __device__ __forceinline__ void bar_wait_fast(unsigned* gff, unsigned v) {
    if (threadIdx.x < 64) {
        for (;;) {
            unsigned f = v;
            if (threadIdx.x < 8)
                f = __hip_atomic_fetch_add(&gff[threadIdx.x], 0u,
                                           __ATOMIC_RELAXED, __HIP_MEMORY_SCOPE_WORKGROUP);
            if (__ballot(f >= v) == ~0ull) break;
            __builtin_amdgcn_s_sleep(1);
        }
    }
    __syncthreads();
}

// ---------------- GRU persistent kernel ----------------
// grid 256 x 256. grp = blk&31 (32 batches), colg = blk>>5 (64 h-cols).
// Group g's blocks {g+32c} all ≡ g (mod 8) -> same XCD under round-robin;
// the handshake verifies the actual exchange mechanism, sc1 fallback else.
__launch_bounds__(256, 1)
__global__ void k_gru(const float* __restrict__ input, const float* __restrict__ hn,
                      const float* __restrict__ W_hh, const float* __restrict__ b_hh,
                      const u16* __restrict__ Weff, const float* __restrict__ beff,
                      u16* __restrict__ hbuf0, u16* __restrict__ hbuf1,
                      unsigned* __restrict__ sflags, unsigned* __restrict__ fflags,
                      unsigned* __restrict__ testc, unsigned* __restrict__ okbuf,
                      unsigned* __restrict__ tokslot, float* __restrict__ hn_out) {
    __shared__ __align__(16) u16 slab[SLAB_ROWS * PITCH];   // 33.3 KB h slab
    __shared__ unsigned fast_sh;

    const int tid  = threadIdx.x;
    const int wave = tid >> 6, lane = tid & 63;
    const int col_l = lane & 15, quad = lane >> 4;
    const int blk = blockIdx.x;
    const int grp = blk & 31, colg = blk >> 5;
    const int grpbase = grp * 32;               // group's 32 batches
    const int cb = colg * 64 + wave * 16;       // wave's 16-col tile base
    unsigned* gflags = sflags + grp * 8;
    unsigned* gff    = fflags + grp * 32;       // 128B-padded fast flags
    unsigned* trow   = testc + grp * 64;        // 256B handshake row

    // hn -> hbuf0 (bf16, sc1, own group's rows) + handshake token (producer)
    {
        int b = grpbase + colg * 4 + wave;
        const float* src = hn + (size_t)b * 512 + lane * 8;
        short8 v;
        #pragma unroll
        for (int e = 0; e < 8; ++e) v[e] = (short)f2bf(src[e]);
        st_h16(hbuf0 + (size_t)b * 512 + lane * 8, v);
    }
    unsigned tok = 0;
    if (colg == 0) {
        u64 rt = __builtin_amdgcn_s_memrealtime();
        tok = ((unsigned)rt ^ (unsigned)(rt >> 32)) | 1u;
        if (tid < 64) trow[tid] = tok;          // plain store -> own L2
        if (tid == 0)
            __hip_atomic_store(&tokslot[grp], tok, __ATOMIC_RELAXED, __HIP_MEMORY_SCOPE_AGENT);
    }
    bar_arrive_slow(gflags, colg, 1u);          // hn + token posted (vmcnt drained)

    // register-resident W_hh B-frags: 3 gates x 16 kc (step-invariant)
    short8 whhf[3][16];
    #pragma unroll
    for (int g3 = 0; g3 < 3; ++g3) {
        const float* wrow = W_hh + (size_t)(g3 * 512 + cb + col_l) * 512;
        #pragma unroll
        for (int kc = 0; kc < 16; ++kc) {
            const float* p = wrow + kc * 32 + quad * 8;
            short8 v;
            #pragma unroll
            for (int e = 0; e < 8; ++e) v[e] = (short)f2bf(p[e]);
            whhf[g3][kc] = v;
        }
    }
    // register-resident W_eff B-frags + per-column biases
    short8 bwx[3];
    float bx[3], bhh[3];
    #pragma unroll
    for (int g3 = 0; g3 < 3; ++g3) {
        int nr = g3 * 512 + cb + col_l;
        bwx[g3] = *(const short8*)(Weff + nr * 32 + quad * 8);
        bx[g3]  = beff[nr];
        bhh[g3] = b_hh[nr];
    }
    // fp32 carried h-state
    float hs[2][4];
    #pragma unroll
    for (int m = 0; m < 2; ++m)
        #pragma unroll
        for (int i = 0; i < 4; ++i)
            hs[m][i] = hn[(size_t)(grpbase + m * 16 + quad * 4 + i) * 512 + cb + col_l];

    // ---- handshake: does remote plain store -> DMA(aux=sc0) see fresh data?
    bar_wait_slow(gflags, 1u);
    unsigned tokv = __hip_atomic_load(&tokslot[grp], __ATOMIC_RELAXED, __HIP_MEMORY_SCOPE_AGENT);
    unsigned* hsk = (unsigned*)slab;            // LDS scratch (pre-loop)
    if (tid < 64) DMA4(trow + lane, hsk + lane);          // attempt L1 population
    bar_arrive_slow(gflags, colg, 2u);          // DMA drained by syncthreads
    bar_wait_slow(gflags, 2u);
    if (colg == 0 && tid < 64) trow[tid] = tokv + 1u;     // remote overwrite
    bar_arrive_slow(gflags, colg, 3u);
    bar_wait_slow(gflags, 3u);
    if (tid < 64) DMA4(trow + lane, hsk + 64 + lane);     // the freshness probe
    __syncthreads();                            // drain DMA, fence LDS
    if (tid < 64) {
        unsigned ok = (hsk[64 + lane] == tokv + 1u) ? 1u : 0u;
        unsigned allok = (__ballot(ok != 0u) == ~0ull) ? 1u : 0u;
        if (tid == 0)
            __hip_atomic_store(&okbuf[grp * 8 + colg], allok,
                               __ATOMIC_RELAXED, __HIP_MEMORY_SCOPE_AGENT);
    }
    bar_arrive_slow(gflags, colg, 4u);          // okbuf drained first
    bar_wait_slow(gflags, 4u);
    if (tid == 0) {
        unsigned all = 1u;
        for (int c = 0; c < 8; ++c)
            all &= __hip_atomic_load(&okbuf[grp * 8 + c], __ATOMIC_RELAXED, __HIP_MEMORY_SCOPE_AGENT);
        fast_sh = all;
    }
    __syncthreads();
    const bool fast = (fast_sh != 0u);          // group-uniform decision

    u16* bufs[2] = { hbuf0, hbuf1 };
    #pragma unroll 1
    for (int t = 0; t < T_STEPS; ++t) {
        const u16* hsrc = bufs[t & 1];
        u16* hdst = bufs[(t + 1) & 1];

        // x loads + gx seed (h-independent; overlaps the barrier wait)
        short8 ax[2];
        #pragma unroll
        for (int m = 0; m < 2; ++m) {
            const float* xp = input + (size_t)(grpbase + m * 16 + col_l) * 4096 + t * 32 + quad * 8;
            float4v a = *(const float4v*)xp;
            float4v b = *(const float4v*)(xp + 4);
            #pragma unroll
            for (int e = 0; e < 4; ++e) { ax[m][e] = (short)f2bf(a[e]); ax[m][4 + e] = (short)f2bf(b[e]); }
        }
        f32x4 z4 = { 0.f, 0.f, 0.f, 0.f };
        f32x4 ar[2], az[2], anx[2], anh[2];
        #pragma unroll
        for (int m = 0; m < 2; ++m) {
            ar[m]  = mfma16(ax[m], bwx[0], z4);
            az[m]  = mfma16(ax[m], bwx[1], z4);
            anx[m] = mfma16(ax[m], bwx[2], z4);
            anh[m] = z4;
        }

        // wait for h(t), stage the 32-row slab (rows rotated by colg)
        if (fast) {
            if (t > 0) bar_wait_fast(gff, (unsigned)t);
            // DMA straight into LDS, 1KB row per instruction, sc0 (L2-fresh)
            #pragma unroll
            for (int r8 = 0; r8 < 8; ++r8) {
                int r = (wave * 8 + r8 + colg * 4) & 31;
                DMA16(hsrc + (size_t)(grpbase + r) * 512 + lane * 8,
                      slab + r * PITCH + lane * 8);
            }
        } else {
            if (t > 0) bar_wait_slow(gflags, (unsigned)(t + 4));
            u64 stg[16];
            #pragma unroll
            for (int r8 = 0; r8 < 8; ++r8) {
                int r = (wave * 8 + r8 + colg * 4) & 31;
                #pragma unroll
                for (int j = 0; j < 2; ++j)
                    stg[r8 * 2 + j] = ld_sc1_u64(hsrc + (size_t)(grpbase + r) * 512 + j * 256 + lane * 4);
            }
            #pragma unroll
            for (int r8 = 0; r8 < 8; ++r8) {
                int r = (wave * 8 + r8 + colg * 4) & 31;
                #pragma unroll
                for (int j = 0; j < 2; ++j)
                    *(u64*)&slab[r * PITCH + j * 256 + lane * 4] = stg[r8 * 2 + j];
            }
        }
        __syncthreads();                        // DMA/writes drained; slab ready

        // ---- compute both m-tiles, reusing register B-frags ----
        #pragma unroll
        for (int m = 0; m < 2; ++m) {
            const int arow = (m * 16 + col_l) * PITCH;
            #pragma unroll
            for (int kc = 0; kc < 16; ++kc) {
                short8 a = *(const short8*)(slab + arow + kc * 32 + quad * 8);  // ds_read_b128
                ar[m]  = mfma16(a, whhf[0][kc], ar[m]);
                az[m]  = mfma16(a, whhf[1][kc], az[m]);
                anh[m] = mfma16(a, whhf[2][kc], anh[m]);
            }
            #pragma unroll
            for (int i = 0; i < 4; ++i) {
                float r = 1.f / (1.f + __expf(-(ar[m][i] + bx[0] + bhh[0])));
                float z = 1.f / (1.f + __expf(-(az[m][i] + bx[1] + bhh[1])));
                float np = anx[m][i] + bx[2] + r * (anh[m][i] + bhh[2]);
                float e  = __expf(-2.f * fabsf(np));
                float nn = __builtin_copysignf((1.f - e) / (1.f + e), np);
                float h  = (1.f - z) * nn + z * hs[m][i];
                hs[m][i] = h;
                int b = grpbase + m * 16 + quad * 4 + i;
                u16 hb = f2bf(h);
                if (fast)
                    hdst[(size_t)b * 512 + cb + col_l] = hb;   // plain -> L2
                else
                    __hip_atomic_store(&hdst[(size_t)b * 512 + cb + col_l], hb,
                                       __ATOMIC_RELAXED, __HIP_MEMORY_SCOPE_AGENT);
            }
        }
        if (t < T_STEPS - 1) {
            if (fast) {
                __syncthreads();                // drain plain h stores to L2
                if (tid == 0)
                    __hip_atomic_fetch_max(&gff[colg], (unsigned)(t + 1),
                                           __ATOMIC_RELAXED, __HIP_MEMORY_SCOPE_WORKGROUP);
            } else {
                bar_arrive_slow(gflags, colg, (unsigned)(t + 5));
            }
        }
    }
    // final hidden state -> d_out hn region (fp32). hbuf0 dirty L2 lines are
    // written back by the end-of-dispatch release for k_head.
    #pragma unroll
    for (int m = 0; m < 2; ++m)
        #pragma unroll
        for (int i = 0; i < 4; ++i)
            hn_out[(size_t)(grpbase + m * 16 + quad * 4 + i) * 512 + cb + col_l] = hs[m][i];
}

// ---------------- epilogue: out2 = relu(relu(h)@W3.T + b3); params = out2.Wh[cult] + bh
__launch_bounds__(256)
__global__ void k_head(const u16* __restrict__ hfin, const float* __restrict__ W3,
                       const float* __restrict__ b3, const int* __restrict__ cult,
                       const float* __restrict__ Wh, const float* __restrict__ bh,
                       float* __restrict__ params) {
    __shared__ float out2[16][264];
    const int tid = threadIdx.x, wave = tid >> 6, lane = tid & 63;
    const int col_l = lane & 15, quad = lane >> 4;
    const int bbase = blockIdx.x * 16;            // 64 blocks x 16 batches

    f32x4 z4 = { 0.f, 0.f, 0.f, 0.f };
    f32x4 acc[4];
    #pragma unroll
    for (int nt = 0; nt < 4; ++nt) acc[nt] = z4;

    #pragma unroll
    for (int kc = 0; kc < 16; ++kc) {
        short8 a = *(const short8*)(hfin + (size_t)(bbase + col_l) * 512 + kc * 32 + quad * 8);
        #pragma unroll
        for (int e = 0; e < 8; ++e) {             // relu on packed bf16 (sign test)
            u16 v = (u16)a[e];
            a[e] = (short)((v & 0x8000u) ? 0 : v);
        }
        #pragma unroll
        for (int nt = 0; nt < 4; ++nt) {
            int nrow = wave * 64 + nt * 16 + col_l;
            const float* wr = W3 + (size_t)nrow * 512 + kc * 32 + quad * 8;
            short8 b;
            #pragma unroll
            for (int e = 0; e < 8; ++e) b[e] = (short)f2bf(wr[e]);
            acc[nt] = mfma16(a, b, acc[nt]);
        }
    }
    #pragma unroll
    for (int nt = 0; nt < 4; ++nt) {
        int ncol = wave * 64 + nt * 16 + col_l;
        float bias = b3[ncol];
        #pragma unroll
        for (int i = 0; i < 4; ++i) {
            float v = acc[nt][i] + bias;
            out2[quad * 4 + i][ncol] = v > 0.f ? v : 0.f;
        }
    }
    __syncthreads();
    int b_local = tid >> 4, o2 = tid & 15;
    int batch = bbase + b_local;
    int c = cult[batch];
    float acc2 = bh[c * 16 + o2];
    const float* wrow = Wh + (size_t)(c * 16 + o2) * 256;
    for (int d = 0; d < 256; ++d) acc2 += out2[b_local][d] * wrow[d];
    params[(size_t)batch * 16 + o2] = acc2;
}

// ---------------- launcher ----------------
extern "C" void kernel_launch(void* const* d_in, const int* in_sizes, int n_in,
                              void* d_out, int out_size, void* d_ws, size_t ws_size,
                              hipStream_t stream) {
    (void)in_sizes; (void)n_in; (void)out_size; (void)ws_size;
    const float* input = (const float*)d_in[0];
    const float* hn    = (const float*)d_in[1];
    const int*   cult  = (const int*)d_in[2];
    const float* W1    = (const float*)d_in[3];
    const float* b1    = (const float*)d_in[4];
    const float* W2    = (const float*)d_in[5];
    const float* b2    = (const float*)d_in[6];
    const float* W_ih  = (const float*)d_in[7];
    const float* W_hh  = (const float*)d_in[8];
    const float* b_ih  = (const float*)d_in[9];
    const float* b_hh  = (const float*)d_in[10];
    const float* W3    = (const float*)d_in[11];
    const float* b3    = (const float*)d_in[12];
    const float* Wh    = (const float*)d_in[13];
    const float* bh    = (const float*)d_in[14];

    char* ws = (char*)d_ws;
    u16*      hbuf0   = (u16*)(ws + WS_HBUF0);
    u16*      hbuf1   = (u16*)(ws + WS_HBUF1);
    float*    W21     = (float*)(ws + WS_W21);
    float*    b21     = (float*)(ws + WS_B21);
    u16*      Weff    = (u16*)(ws + WS_WEFF);
    float*    beff    = (float*)(ws + WS_BEFF);
    unsigned* sflags  = (unsigned*)(ws + WS_SFLAG);
    unsigned* fflags  = (unsigned*)(ws + WS_FFLAG);
    unsigned* testc   = (unsigned*)(ws + WS_TEST);
    unsigned* okbuf   = (unsigned*)(ws + WS_OK);
    unsigned* tokslot = (unsigned*)(ws + WS_TOKS);

    float* out    = (float*)d_out;
    float* params = out;            // 1024*16 fp32
    float* hnout  = out + 16384;    // 1024*512 fp32

    k_prep0<<<64, 256, 0, stream>>>(W1, b1, W2, b2, W21, b21, sflags, fflags);
    k_prep1<<<192, 256, 0, stream>>>(W_ih, b_ih, W21, b21, Weff, beff);
    k_gru<<<256, 256, 0, stream>>>(input, hn, W_hh, b_hh, Weff, beff,
                                   hbuf0, hbuf1, sflags, fflags, testc, okbuf,
                                   tokslot, hnout);
    k_head<<<64, 256, 0, stream>>>(hbuf0, W3, b3, cult, Wh, bh, params);
}

// Round 12
// 755.780 us; speedup vs baseline: 1.0960x; 1.0960x over previous
//
#include <hip/hip_runtime.h>

// ---------------------------------------------------------------------------
// FCGRU (fp32 globals; bf16 in MFMA frags):
//   input(1024,128,32) -> FC(32->256) -> FC(256->512) -> GRU(512) over T=128
//   -> relu -> FC(512->256)+relu -> per-cultivar head (256->16)
// Input-side linears collapse: gx = input @ (W_ih@W2@W1).T + b_eff  (K=32 MFMA).
// Persistent GRU: 32 groups x 8 col-blocks (32 batches/group, 64 cols/block).
// Cross-block h via sc1 (relaxed agent atomics, MALL-coherent; r7-proven).
// Sync-chain tightened vs r7:
//   * per-WAVE flag publish: wave drains its own sc1 h-stores
//     (s_waitcnt(0), vmcnt is per-wave) and lane 0 stores its flag — no block
//     barrier on the inter-block critical path (32 flags/group).
//   * all-wave sleepless polling (one coalesced 128B load per round); the
//     wait needs no __syncthreads — slab is protected by one loop-end barrier.
// W_hh B-frags register-resident (48 short8/wave). PITCH 516 (conflict-free).
// No handshake, no DMA, no inline asm.
// ---------------------------------------------------------------------------

#define T_STEPS 128
#define PITCH   516             // u16 row pitch: 258 dw = 2 mod 32 -> b64 reads free
#define SLAB_ROWS 32

typedef __attribute__((ext_vector_type(8))) short short8;
typedef __attribute__((ext_vector_type(4))) float f32x4;
typedef __attribute__((ext_vector_type(4))) float float4v;
typedef unsigned short u16;
typedef unsigned long long u64;

static __device__ __forceinline__ u16 f2bf(float f) {
    unsigned int u = __builtin_bit_cast(unsigned int, f);
    u += 0x7FFFu + ((u >> 16) & 1u);          // round-to-nearest-even
    return (u16)(u >> 16);
}
static __device__ __forceinline__ f32x4 mfma16(short8 a, short8 b, f32x4 c) {
    return __builtin_amdgcn_mfma_f32_16x16x32_bf16(a, b, c, 0, 0, 0);
}
// device-coherent (MALL) accesses: relaxed agent atomics -> plain sc1 ld/st
static __device__ __forceinline__ void st_h16(u16* p, short8 v) {
    struct W { u64 a, b; } w = __builtin_bit_cast(W, v);
    u64* q = (u64*)p;
    __hip_atomic_store(q + 0, w.a, __ATOMIC_RELAXED, __HIP_MEMORY_SCOPE_AGENT);
    __hip_atomic_store(q + 1, w.b, __ATOMIC_RELAXED, __HIP_MEMORY_SCOPE_AGENT);
}
static __device__ __forceinline__ u64 ld_sc1_u64(const u16* p) {
    return __hip_atomic_load((const u64*)p, __ATOMIC_RELAXED, __HIP_MEMORY_SCOPE_AGENT);
}
// 16B LDS fragment read as two b64 (8B-aligned; PITCH 516 -> conflict-free)
static __device__ __forceinline__ short8 lds8(const u16* p) {
    u64 lo = *(const u64*)p;
    u64 hi = *(const u64*)(p + 4);
    struct W { u64 a, b; } w{lo, hi};
    return __builtin_bit_cast(short8, w);
}

// ---------------- workspace layout (bytes) ----------------
#define WS_HBUF0 0           // 1024*512*2 bf16 h buffer 0
#define WS_HBUF1 1048576     // 1024*512*2 bf16 h buffer 1
#define WS_W21   2097152     // 512*32*4 fp32 W2@W1
#define WS_B21   2162688     // 512*4
#define WS_WEFF  2164736     // 1536*32*2 bf16 W_ih@W2@W1
#define WS_BEFF  2263040     // 1536*4
#define WS_FLAGS 2269184     // 32 groups x 32 slots (block x wave) x 4B = 4096

// ---------------- prologue 0: W21 = W2@W1; b21 = W2@b1 + b2; zero flags
__global__ void k_prep0(const float* __restrict__ W1, const float* __restrict__ b1,
                        const float* __restrict__ W2, const float* __restrict__ b2,
                        float* __restrict__ W21, float* __restrict__ b21,
                        unsigned* __restrict__ flags) {
    if (blockIdx.x == 0) {
        int t = threadIdx.x;
        #pragma unroll
        for (int j = 0; j < 4; ++j)
            __hip_atomic_store(&flags[j * 256 + t], 0u, __ATOMIC_RELAXED, __HIP_MEMORY_SCOPE_AGENT);
    }
    int gid = blockIdx.x * 256 + threadIdx.x;   // 64 blocks: 512*32 outputs
    int k = gid >> 5, d = gid & 31;
    float acc = 0.f;
    for (int j = 0; j < 256; ++j)
        acc += W2[k * 256 + j] * W1[j * 32 + d];
    W21[k * 32 + d] = acc;
    if (d == 0) {
        float bb = b2[k];
        for (int j = 0; j < 256; ++j) bb += W2[k * 256 + j] * b1[j];
        b21[k] = bb;
    }
}

// ---------------- prologue 1: Weff = bf16(W_ih@W21); beff = W_ih@b21 + b_ih
__global__ void k_prep1(const float* __restrict__ W_ih, const float* __restrict__ b_ih,
                        const float* __restrict__ W21, const float* __restrict__ b21,
                        u16* __restrict__ Weff, float* __restrict__ beff) {
    int gid = blockIdx.x * 256 + threadIdx.x;   // 192 blocks: 1536*32 outputs
    int g = gid >> 5, d = gid & 31;
    float acc = 0.f;
    for (int k = 0; k < 512; ++k)
        acc += W_ih[g * 512 + k] * W21[k * 32 + d];
    Weff[g * 32 + d] = f2bf(acc);
    if (d == 0) {
        float bb = b_ih[g];
        for (int k = 0; k < 512; ++k) bb += W_ih[g * 512 + k] * b21[k];
        beff[g] = bb;
    }
}

// ---------------- per-wave publish / all-wave sleepless wait ----------------
// Publish: the wave's own sc1 h-stores are drained by s_waitcnt(0) (vmcnt is
// per-wave), then lane 0 stores the (block,wave) flag. Any consumer that
// observes the flag observes the h data (sc1 -> both at MALL, no stale cache).
static __device__ __forceinline__ void wave_publish(unsigned* gflags, int slot, unsigned v) {
    __builtin_amdgcn_s_waitcnt(0);
    if ((threadIdx.x & 63) == 0)
        __hip_atomic_store(&gflags[slot], v, __ATOMIC_RELAXED, __HIP_MEMORY_SCOPE_AGENT);
}
// Wait: every wave polls all 32 flags (lane i -> flag[i&31]; one coalesced
// 128B read per round, no sleep). No block barrier here.
static __device__ __forceinline__ void bar_wait(const unsigned* gflags, unsigned v) {
    int idx = threadIdx.x & 31;
    for (;;) {
        unsigned f = __hip_atomic_load(&gflags[idx], __ATOMIC_RELAXED, __HIP_MEMORY_SCOPE_AGENT);
        if (__ballot(f >= v) == ~0ull) break;
    }
}

// ---------------- GRU persistent kernel ----------------
// grid 256 x 256. grp = blk&31 (32 batches), colg = blk>>5 (64 h-cols).
// wave w owns col-tile cb = colg*64 + w*16 and computes both 16-row m-tiles.
__launch_bounds__(256, 1)
__global__ void k_gru(const float* __restrict__ input, const float* __restrict__ hn,
                      const float* __restrict__ W_hh, const float* __restrict__ b_hh,
                      const u16* __restrict__ Weff, const float* __restrict__ beff,
                      u16* __restrict__ hbuf0, u16* __restrict__ hbuf1,
                      unsigned* __restrict__ flags, float* __restrict__ hn_out) {
    __shared__ __align__(16) u16 slab[SLAB_ROWS * PITCH];   // 33 KB h slab

    const int tid  = threadIdx.x;
    const int wave = tid >> 6, lane = tid & 63;
    const int col_l = lane & 15, quad = lane >> 4;
    const int blk = blockIdx.x;
    const int grp = blk & 31, colg = blk >> 5;
    const int grpbase = grp * 32;               // group's 32 batches
    const int cb = colg * 64 + wave * 16;       // wave's 16-col tile base
    const int slot = colg * 4 + wave;           // this wave's flag slot
    unsigned* gflags = flags + grp * 32;

    // copy this block's 4 rows of hn -> hbuf0 (bf16, sc1), publish per wave
    {
        int b = grpbase + colg * 4 + wave;       // 8 blocks x 4 rows = 32 ✓
        const float* src = hn + (size_t)b * 512 + lane * 8;
        short8 v;
        #pragma unroll
        for (int e = 0; e < 8; ++e) v[e] = (short)f2bf(src[e]);
        st_h16(hbuf0 + (size_t)b * 512 + lane * 8, v);
    }
    wave_publish(gflags, slot, 1u);              // hn row visible group-wide

    // register-resident W_hh B-frags: 3 gates x 16 kc (step-invariant)
    short8 whhf[3][16];
    #pragma unroll
    for (int g3 = 0; g3 < 3; ++g3) {
        const float* wrow = W_hh + (size_t)(g3 * 512 + cb + col_l) * 512;
        #pragma unroll
        for (int kc = 0; kc < 16; ++kc) {
            const float* p = wrow + kc * 32 + quad * 8;
            short8 v;
            #pragma unroll
            for (int e = 0; e < 8; ++e) v[e] = (short)f2bf(p[e]);
            whhf[g3][kc] = v;
        }
    }
    // register-resident W_eff B-frags (bf16) + per-column biases (fp32)
    short8 bwx[3];
    float bx[3], bhh[3];
    #pragma unroll
    for (int g3 = 0; g3 < 3; ++g3) {
        int nr = g3 * 512 + cb + col_l;
        bwx[g3] = *(const short8*)(Weff + nr * 32 + quad * 8);
        bx[g3]  = beff[nr];
        bhh[g3] = b_hh[nr];
    }
    // fp32 carried h-state: batch = grpbase + m*16 + quad*4 + i, col cb+col_l
    float hs[2][4];
    #pragma unroll
    for (int m = 0; m < 2; ++m)
        #pragma unroll
        for (int i = 0; i < 4; ++i)
            hs[m][i] = hn[(size_t)(grpbase + m * 16 + quad * 4 + i) * 512 + cb + col_l];

    u16* bufs[2] = { hbuf0, hbuf1 };
    #pragma unroll 1
    for (int t = 0; t < T_STEPS; ++t) {
        const u16* hsrc = bufs[t & 1];
        u16* hdst = bufs[(t + 1) & 1];

        // x loads + gx seed (h-independent; overlaps the barrier wait)
        short8 ax[2];
        #pragma unroll
        for (int m = 0; m < 2; ++m) {
            const float* xp = input + (size_t)(grpbase + m * 16 + col_l) * 4096 + t * 32 + quad * 8;
            float4v a = *(const float4v*)xp;
            float4v b = *(const float4v*)(xp + 4);
            #pragma unroll
            for (int e = 0; e < 4; ++e) { ax[m][e] = (short)f2bf(a[e]); ax[m][4 + e] = (short)f2bf(b[e]); }
        }
        f32x4 z4 = { 0.f, 0.f, 0.f, 0.f };
        f32x4 ar[2], az[2], anx[2], anh[2];
        #pragma unroll
        for (int m = 0; m < 2; ++m) {
            ar[m]  = mfma16(ax[m], bwx[0], z4);
            az[m]  = mfma16(ax[m], bwx[1], z4);
            anx[m] = mfma16(ax[m], bwx[2], z4);
            anh[m] = z4;
        }

        bar_wait(gflags, (unsigned)(t + 1));      // h(t) visible group-wide

        // stage the 32-row slab coalesced (lane-contiguous sc1), rows rotated
        // by colg so the 8 blocks of a group don't hit identical MALL lines
        {
            u64 stg[16];
            #pragma unroll
            for (int r8 = 0; r8 < 8; ++r8) {
                int r = (wave * 8 + r8 + colg * 4) & 31;
                #pragma unroll
                for (int j = 0; j < 2; ++j)
                    stg[r8 * 2 + j] = ld_sc1_u64(hsrc + (size_t)(grpbase + r) * 512 + j * 256 + lane * 4);
            }
            #pragma unroll
            for (int r8 = 0; r8 < 8; ++r8) {
                int r = (wave * 8 + r8 + colg * 4) & 31;
                #pragma unroll
                for (int j = 0; j < 2; ++j)
                    *(u64*)&slab[r * PITCH + j * 256 + lane * 4] = stg[r8 * 2 + j];
            }
        }
        __syncthreads();                          // slab ready (all waves wrote)

        // ---- compute both m-tiles, reusing register B-frags ----
        #pragma unroll
        for (int m = 0; m < 2; ++m) {
            const int arow = (m * 16 + col_l) * PITCH;
            #pragma unroll
            for (int kc = 0; kc < 16; ++kc) {
                short8 a = lds8(slab + arow + kc * 32 + quad * 8);
                ar[m]  = mfma16(a, whhf[0][kc], ar[m]);
                az[m]  = mfma16(a, whhf[1][kc], az[m]);
                anh[m] = mfma16(a, whhf[2][kc], anh[m]);
            }
            #pragma unroll
            for (int i = 0; i < 4; ++i) {
                float r = 1.f / (1.f + __expf(-(ar[m][i] + bx[0] + bhh[0])));
                float z = 1.f / (1.f + __expf(-(az[m][i] + bx[1] + bhh[1])));
                float np = anx[m][i] + bx[2] + r * (anh[m][i] + bhh[2]);
                float e  = __expf(-2.f * fabsf(np));
                float nn = __builtin_copysignf((1.f - e) / (1.f + e), np);
                float h  = (1.f - z) * nn + z * hs[m][i];
                hs[m][i] = h;
                int b = grpbase + m * 16 + quad * 4 + i;
                __hip_atomic_store(&hdst[(size_t)b * 512 + cb + col_l], f2bf(h),
                                   __ATOMIC_RELAXED, __HIP_MEMORY_SCOPE_AGENT);
            }
        }
        // publish h(t+1) as soon as THIS wave's stores drain (no block barrier
        // on the inter-block path); then protect the slab for the next step.
        if (t < T_STEPS - 1)
            wave_publish(gflags, slot, (unsigned)(t + 2));
        __syncthreads();                          // all slab reads of step t done
    }
    // final hidden state -> d_out hn region (fp32)
    #pragma unroll
    for (int m = 0; m < 2; ++m)
        #pragma unroll
        for (int i = 0; i < 4; ++i)
            hn_out[(size_t)(grpbase + m * 16 + quad * 4 + i) * 512 + cb + col_l] = hs[m][i];
}

// ---------------- epilogue: out2 = relu(relu(h)@W3.T + b3); params = out2.Wh[cult] + bh
// hfin = bf16 final h (hbuf0: step 127 wrote buffer (127+1)&1 = 0).
__launch_bounds__(256)
__global__ void k_head(const u16* __restrict__ hfin, const float* __restrict__ W3,
                       const float* __restrict__ b3, const int* __restrict__ cult,
                       const float* __restrict__ Wh, const float* __restrict__ bh,
                       float* __restrict__ params) {
    __shared__ float out2[16][264];
    const int tid = threadIdx.x, wave = tid >> 6, lane = tid & 63;
    const int col_l = lane & 15, quad = lane >> 4;
    const int bbase = blockIdx.x * 16;            // 64 blocks x 16 batches

    f32x4 z4 = { 0.f, 0.f, 0.f, 0.f };
    f32x4 acc[4];
    #pragma unroll
    for (int nt = 0; nt < 4; ++nt) acc[nt] = z4;

    #pragma unroll
    for (int kc = 0; kc < 16; ++kc) {
        short8 a = *(const short8*)(hfin + (size_t)(bbase + col_l) * 512 + kc * 32 + quad * 8);
        #pragma unroll
        for (int e = 0; e < 8; ++e) {             // relu on packed bf16 (sign test)
            u16 v = (u16)a[e];
            a[e] = (short)((v & 0x8000u) ? 0 : v);
        }
        #pragma unroll
        for (int nt = 0; nt < 4; ++nt) {
            int nrow = wave * 64 + nt * 16 + col_l;
            const float* wr = W3 + (size_t)nrow * 512 + kc * 32 + quad * 8;
            short8 b;
            #pragma unroll
            for (int e = 0; e < 8; ++e) b[e] = (short)f2bf(wr[e]);
            acc[nt] = mfma16(a, b, acc[nt]);
        }
    }
    #pragma unroll
    for (int nt = 0; nt < 4; ++nt) {
        int ncol = wave * 64 + nt * 16 + col_l;
        float bias = b3[ncol];
        #pragma unroll
        for (int i = 0; i < 4; ++i) {
            float v = acc[nt][i] + bias;
            out2[quad * 4 + i][ncol] = v > 0.f ? v : 0.f;
        }
    }
    __syncthreads();
    // per-cultivar head: 16 batches x 16 outputs = 256 threads, 256-MAC dot each
    int b_local = tid >> 4, o2 = tid & 15;
    int batch = bbase + b_local;
    int c = cult[batch];
    float acc2 = bh[c * 16 + o2];
    const float* wrow = Wh + (size_t)(c * 16 + o2) * 256;
    for (int d = 0; d < 256; ++d) acc2 += out2[b_local][d] * wrow[d];
    params[(size_t)batch * 16 + o2] = acc2;
}

// ---------------- launcher ----------------
extern "C" void kernel_launch(void* const* d_in, const int* in_sizes, int n_in,
                              void* d_out, int out_size, void* d_ws, size_t ws_size,
                              hipStream_t stream) {
    (void)in_sizes; (void)n_in; (void)out_size; (void)ws_size;
    const float* input = (const float*)d_in[0];
    const float* hn    = (const float*)d_in[1];
    const int*   cult  = (const int*)d_in[2];
    const float* W1    = (const float*)d_in[3];
    const float* b1    = (const float*)d_in[4];
    const float* W2    = (const float*)d_in[5];
    const float* b2    = (const float*)d_in[6];
    const float* W_ih  = (const float*)d_in[7];
    const float* W_hh  = (const float*)d_in[8];
    const float* b_ih  = (const float*)d_in[9];
    const float* b_hh  = (const float*)d_in[10];
    const float* W3    = (const float*)d_in[11];
    const float* b3    = (const float*)d_in[12];
    const float* Wh    = (const float*)d_in[13];
    const float* bh    = (const float*)d_in[14];

    char* ws = (char*)d_ws;
    u16*      hbuf0 = (u16*)(ws + WS_HBUF0);
    u16*      hbuf1 = (u16*)(ws + WS_HBUF1);
    float*    W21   = (float*)(ws + WS_W21);
    float*    b21   = (float*)(ws + WS_B21);
    u16*      Weff  = (u16*)(ws + WS_WEFF);
    float*    beff  = (float*)(ws + WS_BEFF);
    unsigned* flags = (unsigned*)(ws + WS_FLAGS);

    float* out    = (float*)d_out;
    float* params = out;            // 1024*16 fp32
    float* hnout  = out + 16384;    // 1024*512 fp32

    k_prep0<<<64, 256, 0, stream>>>(W1, b1, W2, b2, W21, b21, flags);
    k_prep1<<<192, 256, 0, stream>>>(W_ih, b_ih, W21, b21, Weff, beff);
    k_gru<<<256, 256, 0, stream>>>(input, hn, W_hh, b_hh, Weff, beff,
                                   hbuf0, hbuf1, flags, hnout);
    k_head<<<64, 256, 0, stream>>>(hbuf0, W3, b3, cult, Wh, bh, params);
}

// Round 13
// 750.186 us; speedup vs baseline: 1.1041x; 1.0075x over previous
//
#include <hip/hip_runtime.h>

// ---------------------------------------------------------------------------
// FCGRU (fp32 globals; bf16 in MFMA frags):
//   input(1024,128,32) -> FC(32->256) -> FC(256->512) -> GRU(512) over T=128
//   -> relu -> FC(512->256)+relu -> per-cultivar head (256->16)
// Input-side linears collapse: gx = input @ (W_ih@W2@W1).T + b_eff  (K=32 MFMA).
// Persistent GRU: 32 groups x 8 col-blocks (32 batches/group, 64 cols/block).
// Cross-block h via sc1 (relaxed agent atomics, MALL-coherent; r7-proven).
// r13 delta vs r7 (647us): MAILBOX flags. Producer block p stores its epoch
// into 8 per-consumer mailboxes (one 128B line each, threads 0..7); consumer
// polls ONLY its private line. No MALL line is simultaneously read-stormed
// and stored-to -> no store starvation on the flag path.
// W_hh B-frags register-resident (48 short8/wave). 33KB LDS slab, PITCH 516.
// ---------------------------------------------------------------------------

#define T_STEPS 128
#define PITCH   516             // u16 row pitch in LDS: b64 frag reads conflict-free
#define SLAB_ROWS 32

typedef __attribute__((ext_vector_type(8))) short short8;
typedef __attribute__((ext_vector_type(4))) float f32x4;
typedef __attribute__((ext_vector_type(4))) float float4v;
typedef unsigned short u16;
typedef unsigned long long u64;

static __device__ __forceinline__ u16 f2bf(float f) {
    unsigned int u = __builtin_bit_cast(unsigned int, f);
    u += 0x7FFFu + ((u >> 16) & 1u);          // round-to-nearest-even
    return (u16)(u >> 16);
}
static __device__ __forceinline__ f32x4 mfma16(short8 a, short8 b, f32x4 c) {
    return __builtin_amdgcn_mfma_f32_16x16x32_bf16(a, b, c, 0, 0, 0);
}
// device-coherent (MALL) accesses: relaxed agent atomics -> plain sc1 ld/st
static __device__ __forceinline__ void st_h16(u16* p, short8 v) {
    struct W { u64 a, b; } w = __builtin_bit_cast(W, v);
    u64* q = (u64*)p;
    __hip_atomic_store(q + 0, w.a, __ATOMIC_RELAXED, __HIP_MEMORY_SCOPE_AGENT);
    __hip_atomic_store(q + 1, w.b, __ATOMIC_RELAXED, __HIP_MEMORY_SCOPE_AGENT);
}
static __device__ __forceinline__ u64 ld_sc1_u64(const u16* p) {
    return __hip_atomic_load((const u64*)p, __ATOMIC_RELAXED, __HIP_MEMORY_SCOPE_AGENT);
}
// 16B LDS fragment read as two b64 (8B-aligned; PITCH 516 -> conflict-free)
static __device__ __forceinline__ short8 lds8(const u16* p) {
    u64 lo = *(const u64*)p;
    u64 hi = *(const u64*)(p + 4);
    struct W { u64 a, b; } w{lo, hi};
    return __builtin_bit_cast(short8, w);
}

// ---------------- workspace layout (bytes) ----------------
#define WS_HBUF0 0           // 1024*512*2 bf16 h buffer 0
#define WS_HBUF1 1048576     // 1024*512*2 bf16 h buffer 1
#define WS_W21   2097152     // 512*32*4 fp32 W2@W1
#define WS_B21   2162688     // 512*4
#define WS_WEFF  2164736     // 1536*32*2 bf16 W_ih@W2@W1
#define WS_BEFF  2263040     // 1536*4
#define WS_FLAGS 2269184     // mailboxes: 32 grp x 8 consumers x 128B = 32 KB

// ---------------- prologue 0: W21 = W2@W1; b21 = W2@b1 + b2; zero mailboxes
__global__ void k_prep0(const float* __restrict__ W1, const float* __restrict__ b1,
                        const float* __restrict__ W2, const float* __restrict__ b2,
                        float* __restrict__ W21, float* __restrict__ b21,
                        unsigned* __restrict__ flags) {
    if (blockIdx.x == 0) {
        int t = threadIdx.x;
        #pragma unroll
        for (int j = 0; j < 32; ++j)   // 8192 u32 = 32 KB
            __hip_atomic_store(&flags[j * 256 + t], 0u, __ATOMIC_RELAXED, __HIP_MEMORY_SCOPE_AGENT);
    }
    int gid = blockIdx.x * 256 + threadIdx.x;   // 64 blocks: 512*32 outputs
    int k = gid >> 5, d = gid & 31;
    float acc = 0.f;
    for (int j = 0; j < 256; ++j)
        acc += W2[k * 256 + j] * W1[j * 32 + d];
    W21[k * 32 + d] = acc;
    if (d == 0) {
        float bb = b2[k];
        for (int j = 0; j < 256; ++j) bb += W2[k * 256 + j] * b1[j];
        b21[k] = bb;
    }
}

// ---------------- prologue 1: Weff = bf16(W_ih@W21); beff = W_ih@b21 + b_ih
__global__ void k_prep1(const float* __restrict__ W_ih, const float* __restrict__ b_ih,
                        const float* __restrict__ W21, const float* __restrict__ b21,
                        u16* __restrict__ Weff, float* __restrict__ beff) {
    int gid = blockIdx.x * 256 + threadIdx.x;   // 192 blocks: 1536*32 outputs
    int g = gid >> 5, d = gid & 31;
    float acc = 0.f;
    for (int k = 0; k < 512; ++k)
        acc += W_ih[g * 512 + k] * W21[k * 32 + d];
    Weff[g * 32 + d] = f2bf(acc);
    if (d == 0) {
        float bb = b_ih[g];
        for (int k = 0; k < 512; ++k) bb += W_ih[g * 512 + k] * b21[k];
        beff[g] = bb;
    }
}

// ---------------- mailbox barrier (no RMW, no shared poll/store lines) ------
// Group flag region: 8 consumer mailboxes x 128B. Mailbox c, slot p holds the
// epoch of producer p as seen by consumer c.
// Arrive: after __syncthreads() (drains every wave's sc1 h-stores to MALL),
// threads 0..7 store epoch v into mailbox t's slot `colg` (8 lines, 1 store
// instruction). Wait: lanes 0..7 of wave 0 poll ONLY this block's mailbox.
static __device__ __forceinline__ void bar_arrive(unsigned* gmb, int colg, unsigned v) {
    __syncthreads();
    if (threadIdx.x < 8)
        __hip_atomic_store(&gmb[threadIdx.x * 32 + colg], v,
                           __ATOMIC_RELAXED, __HIP_MEMORY_SCOPE_AGENT);
}
static __device__ __forceinline__ void bar_wait(const unsigned* mymb, unsigned v) {
    if (threadIdx.x < 64) {
        int idx = threadIdx.x & 7;
        for (;;) {
            unsigned f = __hip_atomic_load(&mymb[idx], __ATOMIC_RELAXED, __HIP_MEMORY_SCOPE_AGENT);
            if (__ballot(f >= v) == ~0ull) break;
            __builtin_amdgcn_s_sleep(1);
        }
    }
    __syncthreads();
}

// ---------------- GRU persistent kernel ----------------
// grid 256 x 256. grp = blk&31 (32 batches), colg = blk>>5 (64 h-cols).
// wave w owns col-tile cb = colg*64 + w*16 and computes both 16-row m-tiles.
__launch_bounds__(256, 1)
__global__ void k_gru(const float* __restrict__ input, const float* __restrict__ hn,
                      const float* __restrict__ W_hh, const float* __restrict__ b_hh,
                      const u16* __restrict__ Weff, const float* __restrict__ beff,
                      u16* __restrict__ hbuf0, u16* __restrict__ hbuf1,
                      unsigned* __restrict__ flags, float* __restrict__ hn_out) {
    __shared__ __align__(16) u16 slab[SLAB_ROWS * PITCH];   // 33 KB h slab

    const int tid  = threadIdx.x;
    const int wave = tid >> 6, lane = tid & 63;
    const int col_l = lane & 15, quad = lane >> 4;
    const int blk = blockIdx.x;
    const int grp = blk & 31, colg = blk >> 5;
    const int grpbase = grp * 32;               // group's 32 batches
    const int cb = colg * 64 + wave * 16;       // wave's 16-col tile base
    unsigned* gmb  = flags + grp * 256;         // group's 8 mailboxes (u32)
    unsigned* mymb = gmb + colg * 32;           // this block's private line

    // copy this block's 4 rows of hn -> hbuf0 (bf16, sc1, own group's rows)
    {
        int b = grpbase + colg * 4 + wave;       // 8 blocks x 4 rows = 32 ✓
        const float* src = hn + (size_t)b * 512 + lane * 8;
        short8 v;
        #pragma unroll
        for (int e = 0; e < 8; ++e) v[e] = (short)f2bf(src[e]);
        st_h16(hbuf0 + (size_t)b * 512 + lane * 8, v);
    }
    // register-resident W_hh B-frags: 3 gates x 16 kc (step-invariant)
    short8 whhf[3][16];
    #pragma unroll
    for (int g3 = 0; g3 < 3; ++g3) {
        const float* wrow = W_hh + (size_t)(g3 * 512 + cb + col_l) * 512;
        #pragma unroll
        for (int kc = 0; kc < 16; ++kc) {
            const float* p = wrow + kc * 32 + quad * 8;
            short8 v;
            #pragma unroll
            for (int e = 0; e < 8; ++e) v[e] = (short)f2bf(p[e]);
            whhf[g3][kc] = v;
        }
    }
    // register-resident W_eff B-frags (bf16) + per-column biases (fp32)
    short8 bwx[3];
    float bx[3], bhh[3];
    #pragma unroll
    for (int g3 = 0; g3 < 3; ++g3) {
        int nr = g3 * 512 + cb + col_l;
        bwx[g3] = *(const short8*)(Weff + nr * 32 + quad * 8);
        bx[g3]  = beff[nr];
        bhh[g3] = b_hh[nr];
    }
    // fp32 carried h-state: batch = grpbase + m*16 + quad*4 + i, col cb+col_l
    float hs[2][4];
    #pragma unroll
    for (int m = 0; m < 2; ++m)
        #pragma unroll
        for (int i = 0; i < 4; ++i)
            hs[m][i] = hn[(size_t)(grpbase + m * 16 + quad * 4 + i) * 512 + cb + col_l];

    bar_arrive(gmb, colg, 1u);                    // hn staging published

    u16* bufs[2] = { hbuf0, hbuf1 };
    #pragma unroll 1
    for (int t = 0; t < T_STEPS; ++t) {
        const u16* hsrc = bufs[t & 1];
        u16* hdst = bufs[(t + 1) & 1];

        // x loads + gx seed (h-independent; overlaps the barrier wait)
        short8 ax[2];
        #pragma unroll
        for (int m = 0; m < 2; ++m) {
            const float* xp = input + (size_t)(grpbase + m * 16 + col_l) * 4096 + t * 32 + quad * 8;
            float4v a = *(const float4v*)xp;
            float4v b = *(const float4v*)(xp + 4);
            #pragma unroll
            for (int e = 0; e < 4; ++e) { ax[m][e] = (short)f2bf(a[e]); ax[m][4 + e] = (short)f2bf(b[e]); }
        }
        f32x4 z4 = { 0.f, 0.f, 0.f, 0.f };
        f32x4 ar[2], az[2], anx[2], anh[2];
        #pragma unroll
        for (int m = 0; m < 2; ++m) {
            ar[m]  = mfma16(ax[m], bwx[0], z4);
            az[m]  = mfma16(ax[m], bwx[1], z4);
            anx[m] = mfma16(ax[m], bwx[2], z4);
            anh[m] = z4;
        }

        bar_wait(mymb, (unsigned)(t + 1));        // h(t) visible group-wide

        // stage the 32-row slab coalesced (lane-contiguous sc1), rows rotated
        // by colg so the 8 blocks of a group don't hit identical MALL lines
        {
            u64 stg[16];
            #pragma unroll
            for (int r8 = 0; r8 < 8; ++r8) {
                int r = (wave * 8 + r8 + colg * 4) & 31;
                #pragma unroll
                for (int j = 0; j < 2; ++j)
                    stg[r8 * 2 + j] = ld_sc1_u64(hsrc + (size_t)(grpbase + r) * 512 + j * 256 + lane * 4);
            }
            #pragma unroll
            for (int r8 = 0; r8 < 8; ++r8) {
                int r = (wave * 8 + r8 + colg * 4) & 31;
                #pragma unroll
                for (int j = 0; j < 2; ++j)
                    *(u64*)&slab[r * PITCH + j * 256 + lane * 4] = stg[r8 * 2 + j];
            }
        }
        __syncthreads();                          // slab ready

        // ---- compute both m-tiles, reusing register B-frags ----
        #pragma unroll
        for (int m = 0; m < 2; ++m) {
            const int arow = (m * 16 + col_l) * PITCH;
            #pragma unroll
            for (int kc = 0; kc < 16; ++kc) {
                short8 a = lds8(slab + arow + kc * 32 + quad * 8);
                ar[m]  = mfma16(a, whhf[0][kc], ar[m]);
                az[m]  = mfma16(a, whhf[1][kc], az[m]);
                anh[m] = mfma16(a, whhf[2][kc], anh[m]);
            }
            #pragma unroll
            for (int i = 0; i < 4; ++i) {
                float r = 1.f / (1.f + __expf(-(ar[m][i] + bx[0] + bhh[0])));
                float z = 1.f / (1.f + __expf(-(az[m][i] + bx[1] + bhh[1])));
                float np = anx[m][i] + bx[2] + r * (anh[m][i] + bhh[2]);
                float e  = __expf(-2.f * fabsf(np));
                float nn = __builtin_copysignf((1.f - e) / (1.f + e), np);
                float h  = (1.f - z) * nn + z * hs[m][i];
                hs[m][i] = h;
                int b = grpbase + m * 16 + quad * 4 + i;
                __hip_atomic_store(&hdst[(size_t)b * 512 + cb + col_l], f2bf(h),
                                   __ATOMIC_RELAXED, __HIP_MEMORY_SCOPE_AGENT);
            }
        }
        if (t < T_STEPS - 1)
            bar_arrive(gmb, colg, (unsigned)(t + 2));   // publish h(t+1)
    }
    // final hidden state -> d_out hn region (fp32)
    #pragma unroll
    for (int m = 0; m < 2; ++m)
        #pragma unroll
        for (int i = 0; i < 4; ++i)
            hn_out[(size_t)(grpbase + m * 16 + quad * 4 + i) * 512 + cb + col_l] = hs[m][i];
}

// ---------------- epilogue: out2 = relu(relu(h)@W3.T + b3); params = out2.Wh[cult] + bh
// hfin = bf16 final h (hbuf0: step 127 wrote buffer (127+1)&1 = 0).
__launch_bounds__(256)
__global__ void k_head(const u16* __restrict__ hfin, const float* __restrict__ W3,
                       const float* __restrict__ b3, const int* __restrict__ cult,
                       const float* __restrict__ Wh, const float* __restrict__ bh,
                       float* __restrict__ params) {
    __shared__ float out2[16][264];
    const int tid = threadIdx.x, wave = tid >> 6, lane = tid & 63;
    const int col_l = lane & 15, quad = lane >> 4;
    const int bbase = blockIdx.x * 16;            // 64 blocks x 16 batches

    f32x4 z4 = { 0.f, 0.f, 0.f, 0.f };
    f32x4 acc[4];
    #pragma unroll
    for (int nt = 0; nt < 4; ++nt) acc[nt] = z4;

    #pragma unroll
    for (int kc = 0; kc < 16; ++kc) {
        short8 a = *(const short8*)(hfin + (size_t)(bbase + col_l) * 512 + kc * 32 + quad * 8);
        #pragma unroll
        for (int e = 0; e < 8; ++e) {             // relu on packed bf16 (sign test)
            u16 v = (u16)a[e];
            a[e] = (short)((v & 0x8000u) ? 0 : v);
        }
        #pragma unroll
        for (int nt = 0; nt < 4; ++nt) {
            int nrow = wave * 64 + nt * 16 + col_l;
            const float* wr = W3 + (size_t)nrow * 512 + kc * 32 + quad * 8;
            short8 b;
            #pragma unroll
            for (int e = 0; e < 8; ++e) b[e] = (short)f2bf(wr[e]);
            acc[nt] = mfma16(a, b, acc[nt]);
        }
    }
    #pragma unroll
    for (int nt = 0; nt < 4; ++nt) {
        int ncol = wave * 64 + nt * 16 + col_l;
        float bias = b3[ncol];
        #pragma unroll
        for (int i = 0; i < 4; ++i) {
            float v = acc[nt][i] + bias;
            out2[quad * 4 + i][ncol] = v > 0.f ? v : 0.f;
        }
    }
    __syncthreads();
    // per-cultivar head: 16 batches x 16 outputs = 256 threads, 256-MAC dot each
    int b_local = tid >> 4, o2 = tid & 15;
    int batch = bbase + b_local;
    int c = cult[batch];
    float acc2 = bh[c * 16 + o2];
    const float* wrow = Wh + (size_t)(c * 16 + o2) * 256;
    for (int d = 0; d < 256; ++d) acc2 += out2[b_local][d] * wrow[d];
    params[(size_t)batch * 16 + o2] = acc2;
}

// ---------------- launcher ----------------
extern "C" void kernel_launch(void* const* d_in, const int* in_sizes, int n_in,
                              void* d_out, int out_size, void* d_ws, size_t ws_size,
                              hipStream_t stream) {
    (void)in_sizes; (void)n_in; (void)out_size; (void)ws_size;
    const float* input = (const float*)d_in[0];
    const float* hn    = (const float*)d_in[1];
    const int*   cult  = (const int*)d_in[2];
    const float* W1    = (const float*)d_in[3];
    const float* b1    = (const float*)d_in[4];
    const float* W2    = (const float*)d_in[5];
    const float* b2    = (const float*)d_in[6];
    const float* W_ih  = (const float*)d_in[7];
    const float* W_hh  = (const float*)d_in[8];
    const float* b_ih  = (const float*)d_in[9];
    const float* b_hh  = (const float*)d_in[10];
    const float* W3    = (const float*)d_in[11];
    const float* b3    = (const float*)d_in[12];
    const float* Wh    = (const float*)d_in[13];
    const float* bh    = (const float*)d_in[14];

    char* ws = (char*)d_ws;
    u16*      hbuf0 = (u16*)(ws + WS_HBUF0);
    u16*      hbuf1 = (u16*)(ws + WS_HBUF1);
    float*    W21   = (float*)(ws + WS_W21);
    float*    b21   = (float*)(ws + WS_B21);
    u16*      Weff  = (u16*)(ws + WS_WEFF);
    float*    beff  = (float*)(ws + WS_BEFF);
    unsigned* flags = (unsigned*)(ws + WS_FLAGS);

    float* out    = (float*)d_out;
    float* params = out;            // 1024*16 fp32
    float* hnout  = out + 16384;    // 1024*512 fp32

    k_prep0<<<64, 256, 0, stream>>>(W1, b1, W2, b2, W21, b21, flags);
    k_prep1<<<192, 256, 0, stream>>>(W_ih, b_ih, W21, b21, Weff, beff);
    k_gru<<<256, 256, 0, stream>>>(input, hn, W_hh, b_hh, Weff, beff,
                                   hbuf0, hbuf1, flags, hnout);
    k_head<<<64, 256, 0, stream>>>(hbuf0, W3, b3, cult, Wh, bh, params);
}